// Round 1
// baseline (1073.386 us; speedup 1.0000x reference)
//
#include <hip/hip_runtime.h>
#include <math.h>

// PhyloNeighbours: per-filter (16) kNN (k=8) over 2000 features, 512-dim coords.
// v6: approx kernel pipelined — async global_load_lds staging (direct to LDS,
// no register temps), double-buffered A/B tiles across kc, counted
// s_waitcnt vmcnt(12) + raw s_barrier so next tile's loads stay in flight
// across the whole MFMA phase (T3+T4). XOR swizzle preserved by pre-swizzling
// the per-lane GLOBAL source address (LDS dest stays linear; swizzle is an
// involution so source-permute == read-permute). LDS 97KB -> 1 block/CU,
// 512 blocks = 2 clean rounds; latency hiding now comes from the pipeline,
// not TLP. Arithmetic identical to v5 (validated): candidates top-10/chunk,
// refine/select exact.
//
// Memory plan:
//   d_out: phase 1 holds cbt[f][2048][512] bf16 (32 MB); phase 2 holds
//          ct[f][2000][512] fp32 (exactly out_size floats); final gather output.
//   d_ws : sq 128KB + cand 2.56MB + dval 2.56MB + fidx 1MB ~= 6.3 MB.

#define F_TOT 2000
#define CF    16
#define KDIM  512
#define NB_K  8
#define IPAD  2048
#define NCAND 10
#define NCH   2
#define NCTOT (NCAND * NCH)

typedef __attribute__((ext_vector_type(8))) short bf16x8;
typedef __attribute__((ext_vector_type(4))) float f32x4;

__device__ inline unsigned short f2bf(float x) {
  unsigned int u = __float_as_uint(x);
  return (unsigned short)((u + 0x7fffu + ((u >> 16) & 1u)) >> 16);
}

// async 16B global -> LDS (LDS dest: wave-uniform base + lane*16)
#define GLOAD_LDS16(gp, lp)                                                          \
  __builtin_amdgcn_global_load_lds((const __attribute__((address_space(1))) void*)(gp), \
                                   (__attribute__((address_space(3))) void*)(lp), 16, 0, 0)

// ---------------------------------------------------------------- k1: sq (fp64)
// VALIDATED rounds 1-4 — do not change arithmetic.
__global__ __launch_bounds__(256) void sq_kernel(const float* __restrict__ coords,
                                                 float* __restrict__ sq_out) {
  int i = blockIdx.x;
  int t = threadIdx.x;
  int f = t & 15;
  int cg = t >> 4;
  const float* base = coords + (size_t)i * CF + f;
  double s = 0.0;
  for (int c = cg * 32; c < cg * 32 + 32; ++c) {
    float v = base[(size_t)c * (F_TOT * CF)];
    s += (double)v * (double)v;
  }
  __shared__ double red[256];
  red[t] = s;
  __syncthreads();
  if (cg == 0) {
    double tot = 0.0;
#pragma unroll
    for (int g = 0; g < 16; ++g) tot += red[g * 16 + f];
    sq_out[i * CF + f] = (float)tot;
  }
}

// ------------------------------------------- k2: coords -> cbt[f][i pad2048][c] bf16
__global__ __launch_bounds__(256) void cvt_bf16_kernel(const float* __restrict__ coords,
                                                       unsigned short* __restrict__ cbt) {
  __shared__ float lds[32 * 257];
  const int i0 = blockIdx.x * 16;    // 0..2032
  const int c0 = blockIdx.y * 32;
  const int t = threadIdx.x;
  const int io = t >> 4, f = t & 15;
  const int iclamp = min(i0 + io, F_TOT - 1);
  for (int cc = 0; cc < 32; ++cc)
    lds[cc * 257 + t] = coords[(size_t)(c0 + cc) * (F_TOT * CF) + iclamp * CF + f];
  __syncthreads();
  size_t obase = ((size_t)f * IPAD + (i0 + io)) * KDIM + c0;
#pragma unroll
  for (int cc = 0; cc < 32; cc += 4) {
    unsigned int lo = (unsigned int)f2bf(lds[(cc + 0) * 257 + t]) |
                      ((unsigned int)f2bf(lds[(cc + 1) * 257 + t]) << 16);
    unsigned int hi = (unsigned int)f2bf(lds[(cc + 2) * 257 + t]) |
                      ((unsigned int)f2bf(lds[(cc + 3) * 257 + t]) << 16);
    *(uint2*)(cbt + obase + cc) = make_uint2(lo, hi);
  }
}

// ------------------------------------------- k4: coords -> ct[f][i 2000][c] fp32
__global__ __launch_bounds__(256) void cvt_f32t_kernel(const float* __restrict__ coords,
                                                       float* __restrict__ ct) {
  __shared__ float lds[32 * 257];
  const int i0 = blockIdx.x * 16;    // 0..1984 (125 tiles exact)
  const int c0 = blockIdx.y * 32;
  const int t = threadIdx.x;
  const int io = t >> 4;
  for (int cc = 0; cc < 32; ++cc)
    lds[cc * 257 + t] = coords[(size_t)(c0 + cc) * (F_TOT * CF) + i0 * CF + t];
  __syncthreads();
  const int f = t & 15;
  size_t obase = ((size_t)f * F_TOT + (i0 + io)) * KDIM + c0;
#pragma unroll
  for (int cc = 0; cc < 32; cc += 4) {
    float4 v = make_float4(lds[(cc + 0) * 257 + t], lds[(cc + 1) * 257 + t],
                           lds[(cc + 2) * 257 + t], lds[(cc + 3) * 257 + t]);
    *(float4*)(ct + obase + cc) = v;
  }
}

// ------------------------------------------- k3: bf16 MFMA approx + top-10/chunk
// grid 512: f = bx&15, i-tile(128) = (bx>>4)&15, j-chunk(1000) = bx>>8.
// v6 staging: global_load_lds direct to LDS, double-buffered over kc.
// LDS slot s (linear, 16B units) holds global (row=s>>3, seg=(s&7)^(row&7)),
// so phys slot (r, p) holds global (r, p^(r&7)) — identical layout to v5's
// explicit swizzled ds_writes; fragment reads unchanged.
__global__ __launch_bounds__(256, 1) void approx_kernel(const unsigned short* __restrict__ cbt,
                                                        const float* __restrict__ sq,
                                                        int* __restrict__ cand) {
  const int bx = blockIdx.x;
  const int f = bx & 15;
  const int it = (bx >> 4) & 15;
  const int jc = bx >> 8;
  const int ibase = it * 128;
  const int jcbase = jc * 1000;
  const int jlimit = jcbase + 1000;

  const int t = threadIdx.x;
  const int lane = t & 63;
  const int w = t >> 6;
  const int wi = w & 1, wj = w >> 1;
  const int lrow = lane & 15, lq = lane >> 4;

  // A0 [0,16K) A1 [16K,32K) B0 [32K,64K) B1 [64K,96K) sqj [96K,97K)
  // Dl [128][128] f32 aliases A0+A1+B0 (B1 is dead during epilogue/scan).
  __shared__ char smem[99328];
  char* A0p = smem;
  char* A1p = smem + 16384;
  char* B0p = smem + 32768;
  char* B1p = smem + 65536;
  float* Dl = (float*)smem;
  float* sqj = (float*)(smem + 98304);

  const unsigned short* abase_g = cbt + ((size_t)f * IPAD + ibase) * KDIM;

  // scan identity: row ii, j-half (64 j per 128-j phase)
  const int ii = t & 127;
  const int half = t >> 7;
  const bool rowok = (ibase + ii < F_TOT);

  float bv[NCAND]; int bi[NCAND];
#pragma unroll
  for (int k = 0; k < NCAND; ++k) { bv[k] = __builtin_inff(); bi[k] = 0x7fffffff; }
  float sqi = rowok ? sq[(ibase + ii) * CF + f] : 0.0f;

  // A-fragment row geometry (per mi)
  int arow[4];
#pragma unroll
  for (int mi = 0; mi < 4; ++mi) arow[mi] = wi * 64 + mi * 16 + lrow;
  int brow[8];
#pragma unroll
  for (int nj = 0; nj < 8; ++nj) brow[nj] = wj * 128 + nj * 16 + lrow;

  for (int js = 0; js < 4; ++js) {
    const int jbase = jcbase + js * 256;
    __syncthreads();   // previous js's scan (Dl/sqj readers) done; staging may begin
    { int jg = jbase + t; sqj[t] = (jg < F_TOT) ? sq[jg * CF + f] : 0.0f; }

    f32x4 acc[4][8];
#pragma unroll
    for (int mi = 0; mi < 4; ++mi)
#pragma unroll
      for (int nj = 0; nj < 8; ++nj) acc[mi][nj] = (f32x4){0.f, 0.f, 0.f, 0.f};

    const unsigned short* bbase_g = cbt + ((size_t)f * IPAD + jbase) * KDIM;

    // issue one 64-col tile of A (4 instr) + B (8 instr) into (Ad, Bd).
    // source address pre-swizzled: LDS slot s=(p*256+t) <- global (s>>3, (s&7)^((s>>3)&7))
#define STAGE_AB(Ad, Bd, c0)                                                          \
    {                                                                                 \
      _Pragma("unroll")                                                               \
      for (int p = 0; p < 4; ++p) {                                                   \
        int s = p * 256 + t;                                                          \
        int r = s >> 3, sg = s & 7;                                                   \
        GLOAD_LDS16(abase_g + (size_t)r * KDIM + (c0) + ((sg ^ (r & 7)) << 3),        \
                    (Ad) + p * 4096 + (w << 10));                                     \
      }                                                                               \
      _Pragma("unroll")                                                               \
      for (int p = 0; p < 8; ++p) {                                                   \
        int s = p * 256 + t;                                                          \
        int r = s >> 3, sg = s & 7;                                                   \
        GLOAD_LDS16(bbase_g + (size_t)r * KDIM + (c0) + ((sg ^ (r & 7)) << 3),        \
                    (Bd) + p * 4096 + (w << 10));                                     \
      }                                                                               \
    }

    STAGE_AB(A0p, B0p, 0);            // prologue: kc=0 into buf0

    for (int kc = 0; kc < 8; ++kc) {
      const unsigned short* Al = (const unsigned short*)((kc & 1) ? A1p : A0p);
      const unsigned short* Bl = (const unsigned short*)((kc & 1) ? B1p : B0p);
      // #1: all waves done reading the buffer we are about to overwrite
      __builtin_amdgcn_s_barrier();
      if (kc < 7) {
        STAGE_AB((kc & 1) ? A0p : A1p, (kc & 1) ? B0p : B1p, (kc + 1) * 64);
        // wait only the OLDER 12 (current buffer); the 12 just issued stay in flight
        asm volatile("s_waitcnt vmcnt(12)" ::: "memory");
      } else {
        asm volatile("s_waitcnt vmcnt(0)" ::: "memory");
      }
      // #2: every wave has waited its own loads -> buf[cur] fully populated
      __builtin_amdgcn_s_barrier();
      __builtin_amdgcn_sched_barrier(0);   // keep ds_reads below the fence
#pragma unroll
      for (int ks = 0; ks < 2; ++ks) {
        bf16x8 a[4];
#pragma unroll
        for (int mi = 0; mi < 4; ++mi) {
          int sg = ks * 4 + lq;
          a[mi] = *(const bf16x8*)(Al + arow[mi] * 64 + ((sg ^ (arow[mi] & 7)) << 3));
        }
#pragma unroll
        for (int nj = 0; nj < 8; ++nj) {
          int sg = ks * 4 + lq;
          bf16x8 b = *(const bf16x8*)(Bl + brow[nj] * 64 + ((sg ^ (brow[nj] & 7)) << 3));
#pragma unroll
          for (int mi = 0; mi < 4; ++mi)
            acc[mi][nj] = __builtin_amdgcn_mfma_f32_16x16x32_bf16(a[mi], b, acc[mi][nj], 0, 0, 0);
        }
      }
    }
#undef STAGE_AB

    // epilogue + scan: two phases of 128 j, all 256 threads scan
#pragma unroll
    for (int ph = 0; ph < 2; ++ph) {
      __syncthreads();
      if (wj == ph) {                          // these waves hold block-j [ph*128, +128)
#pragma unroll
        for (int mi = 0; mi < 4; ++mi) {
#pragma unroll
          for (int nj = 0; nj < 8; ++nj) {
#pragma unroll
            for (int r = 0; r < 4; ++r) {
              int row = wi * 64 + mi * 16 + lq * 4 + r;   // C: col=lane&15, row=quad*4+reg
              int col = nj * 16 + lrow;
              int q = col >> 2, rr = col & 3;
              Dl[row * 128 + (((q ^ (row & 7))) << 2) + rr] = acc[mi][nj][r];
            }
          }
        }
      }
      __syncthreads();
      if (rowok) {
        const int j0 = jbase + ph * 128 + half * 64;
        int cnt = jlimit - j0; if (cnt > 64) cnt = 64;
        for (int bb = 0; bb < 16; ++bb) {
          const int bo = bb * 4;
          if (bo >= cnt) break;
          const int qq = half * 16 + bb;
          const float4 g4 = *(const float4*)&Dl[ii * 128 + ((qq ^ (ii & 7)) << 2)];
          const float4 s4 = *(const float4*)&sqj[ph * 128 + half * 64 + bo];
          float d0 = fmaxf(fmaf(-2.0f, g4.x, sqi + s4.x), 0.0f);
          float d1 = fmaxf(fmaf(-2.0f, g4.y, sqi + s4.y), 0.0f);
          float d2 = fmaxf(fmaf(-2.0f, g4.z, sqi + s4.z), 0.0f);
          float d3 = fmaxf(fmaf(-2.0f, g4.w, sqi + s4.w), 0.0f);
          const int rem = cnt - bo;
          if (rem < 4) d3 = __builtin_inff();
          if (rem < 3) d2 = __builtin_inff();
          if (rem < 2) d1 = __builtin_inff();
          float mn = fminf(fminf(d0, d1), fminf(d2, d3));
          if (mn <= bv[NCAND - 1]) {           // gate; exact lex insert inside
            float dd[4] = {d0, d1, d2, d3};
#pragma unroll
            for (int e = 0; e < 4; ++e) {      // ascending j within the quad
              float d = dd[e]; int jg = j0 + bo + e;
              if (d < bv[NCAND - 1] || (d == bv[NCAND - 1] && jg < bi[NCAND - 1])) {
                float cv = d; int ci = jg;
#pragma unroll
                for (int k = 0; k < NCAND; ++k) {
                  bool lt = (cv < bv[k]) || (cv == bv[k] && ci < bi[k]);
                  float tv = lt ? bv[k] : cv; int ti = lt ? bi[k] : ci;
                  bv[k] = lt ? cv : bv[k];    bi[k] = lt ? ci : bi[k];
                  cv = tv; ci = ti;
                }
              }
            }
          }
        }
      }
    }
  }

  // merge the two j-half partial top-10s (lex-exact == chunk top-10)
  __syncthreads();
  if (half == 1 && rowok) {
    float* wrow = &Dl[ii * 128];
#pragma unroll
    for (int k = 0; k < NCAND; ++k) { wrow[k] = bv[k]; *(int*)&wrow[NCAND + k] = bi[k]; }
  }
  __syncthreads();
  if (half == 0 && rowok) {
    const float* wrow = &Dl[ii * 128];
    float ov[NCAND]; int oi[NCAND];
#pragma unroll
    for (int k = 0; k < NCAND; ++k) { ov[k] = wrow[k]; oi[k] = *(const int*)&wrow[NCAND + k]; }
    float mv[NCAND]; int mj[NCAND];
    int p = 0, q = 0;
#pragma unroll
    for (int k = 0; k < NCAND; ++k) {          // two-pointer lex merge, pick 10 smallest
      bool mine = (q >= NCAND) || ((p < NCAND) &&
                  ((bv[p] < ov[q]) || (bv[p] == ov[q] && bi[p] < oi[q])));
      mv[k] = mine ? bv[p] : ov[q];
      mj[k] = mine ? bi[p] : oi[q];
      p += mine ? 1 : 0; q += mine ? 0 : 1;
    }
    (void)mv;
    // sort the 10 candidate j's ascending (odd-even transposition)
#pragma unroll
    for (int r = 0; r < NCAND; ++r) {
#pragma unroll
      for (int k = 0; k + 1 < NCAND; ++k) {
        if (((k ^ r) & 1) == 0) {
          int lo = min(mj[k], mj[k + 1]);
          int hi = max(mj[k], mj[k + 1]);
          mj[k] = lo; mj[k + 1] = hi;
        }
      }
    }
    int* dst = cand + ((size_t)(ibase + ii) * CF + f) * NCTOT + jc * NCAND;
#pragma unroll
    for (int k = 0; k < NCAND; ++k) dst[k] = mj[k];
  }
}

// ------------------------------------------- k5: exact distances, 2 cands/thread
// VALIDATED arithmetic — ascending-c fmaf chain. 20 cands -> 10 pairs per (i,f).
__global__ __launch_bounds__(256) void refine_dist_kernel(const float* __restrict__ ct,
                                                          const float* __restrict__ sq,
                                                          const int* __restrict__ cand,
                                                          float* __restrict__ dval) {
  int x = blockIdx.x * 256 + threadIdx.x;    // 0..319999
  if (x >= F_TOT * CF * (NCTOT / 2)) return;
  int pf = x / (NCTOT / 2);
  int m = x - pf * (NCTOT / 2);
  int i = pf >> 4, f = pf & 15;
  const float* a = ct + ((size_t)f * F_TOT + i) * KDIM;
  float sqi = sq[i * CF + f];
  int j0 = cand[(size_t)pf * NCTOT + 2 * m];
  int j1 = cand[(size_t)pf * NCTOT + 2 * m + 1];
  const float* p = ct + ((size_t)f * F_TOT + j0) * KDIM;
  const float* q = ct + ((size_t)f * F_TOT + j1) * KDIM;
  float g0 = 0.0f, g1 = 0.0f;
  for (int c = 0; c < KDIM; c += 8) {
    float4 a0 = *(const float4*)(a + c), a1 = *(const float4*)(a + c + 4);
    float4 p0 = *(const float4*)(p + c), p1 = *(const float4*)(p + c + 4);
    float4 q0 = *(const float4*)(q + c), q1 = *(const float4*)(q + c + 4);
    g0 = fmaf(a0.x, p0.x, g0); g1 = fmaf(a0.x, q0.x, g1);
    g0 = fmaf(a0.y, p0.y, g0); g1 = fmaf(a0.y, q0.y, g1);
    g0 = fmaf(a0.z, p0.z, g0); g1 = fmaf(a0.z, q0.z, g1);
    g0 = fmaf(a0.w, p0.w, g0); g1 = fmaf(a0.w, q0.w, g1);
    g0 = fmaf(a1.x, p1.x, g0); g1 = fmaf(a1.x, q1.x, g1);
    g0 = fmaf(a1.y, p1.y, g0); g1 = fmaf(a1.y, q1.y, g1);
    g0 = fmaf(a1.z, p1.z, g0); g1 = fmaf(a1.z, q1.z, g1);
    g0 = fmaf(a1.w, p1.w, g0); g1 = fmaf(a1.w, q1.w, g1);
  }
  float d0 = fmaf(-2.0f, g0, sqi + sq[j0 * CF + f]); d0 = fmaxf(d0, 0.0f);
  float d1 = fmaf(-2.0f, g1, sqi + sq[j1 * CF + f]); d1 = fmaxf(d1, 0.0f);
  dval[(size_t)pf * NCTOT + 2 * m]     = d0;
  dval[(size_t)pf * NCTOT + 2 * m + 1] = d1;
}

// ------------------------------------------- k6: top-8 select (ascending-j, strict <)
__global__ __launch_bounds__(256) void select_kernel(const float* __restrict__ dval,
                                                     const int* __restrict__ cand,
                                                     int* __restrict__ fidx) {
  int pf = blockIdx.x * 256 + threadIdx.x;   // (i*16+f), 0..31999
  if (pf >= F_TOT * CF) return;
  int i = pf >> 4, f = pf & 15;
  float bval[NB_K]; int bidx[NB_K];
#pragma unroll
  for (int k = 0; k < NB_K; ++k) { bval[k] = __builtin_inff(); bidx[k] = 0; }
#pragma unroll
  for (int m = 0; m < NCTOT; ++m) {          // ascending j (chunks disjoint ascending)
    float d = dval[(size_t)pf * NCTOT + m];
    int j = cand[(size_t)pf * NCTOT + m];
    if (d < bval[NB_K - 1]) {
      float cv = d; int ci = j;
#pragma unroll
      for (int k = 0; k < NB_K; ++k)
        if (cv < bval[k]) {
          float tv = bval[k]; bval[k] = cv; cv = tv;
          int ti = bidx[k]; bidx[k] = ci; ci = ti;
        }
    }
  }
#pragma unroll
  for (int k = 0; k < NB_K; ++k)
    fidx[((size_t)i * NB_K + k) * CF + f] = bidx[k];
}

// ---------------------------------------------------------------- k7: gather
__global__ __launch_bounds__(256) void gather_kernel(const float* __restrict__ inputs,
                                                     const int* __restrict__ fidx,
                                                     float* __restrict__ out) {
  int b = blockIdx.y;
  int x = blockIdx.x * 256 + threadIdx.x;    // m*16+c
  int c = x & 15;
  int n = fidx[x];
  out[(size_t)b * (F_TOT * NB_K * CF) + x] =
      inputs[(size_t)b * (F_TOT * CF) + n * CF + c];
}

// ---------------------------------------------------------------- launcher
extern "C" void kernel_launch(void* const* d_in, const int* in_sizes, int n_in,
                              void* d_out, int out_size, void* d_ws, size_t ws_size,
                              hipStream_t stream) {
  const float* inputs = (const float*)d_in[0];   // (64, 2000, 16)
  const float* coords = (const float*)d_in[1];   // (512, 2000, 16)
  float* out = (float*)d_out;

  unsigned short* cbt = (unsigned short*)d_out;  // 16*2048*512 bf16 (phase 1)
  float* ct = (float*)d_out;                     // 16*2000*512 f32 (phase 2, == out_size)

  float* sq = (float*)d_ws;                      // 32768 floats
  int* cand = (int*)d_ws + 32768;                // 32000*20 ints
  float* dval = (float*)d_ws + 32768 + 32000 * NCTOT; // 32000*20 floats
  int* fidx = (int*)d_ws + 32768 + 2 * 32000 * NCTOT; // 256000 ints

  sq_kernel<<<F_TOT, 256, 0, stream>>>(coords, sq);
  cvt_bf16_kernel<<<dim3(IPAD / 16, KDIM / 32), 256, 0, stream>>>(coords, cbt);
  approx_kernel<<<512, 256, 0, stream>>>(cbt, sq, cand);
  cvt_f32t_kernel<<<dim3(F_TOT / 16, KDIM / 32), 256, 0, stream>>>(coords, ct);
  refine_dist_kernel<<<(F_TOT * CF * (NCTOT / 2) + 255) / 256, 256, 0, stream>>>(ct, sq, cand, dval);
  select_kernel<<<(F_TOT * CF + 255) / 256, 256, 0, stream>>>(dval, cand, fidx);
  dim3 g7((F_TOT * NB_K * CF) / 256, 64);
  gather_kernel<<<g7, 256, 0, stream>>>(inputs, fidx, out);
}

// Round 2
// 878.811 us; speedup vs baseline: 1.2214x; 1.2214x over previous
//
#include <hip/hip_runtime.h>
#include <math.h>

// PhyloNeighbours: per-filter (16) kNN (k=8) over 2000 features, 512-dim coords.
// v7: v6's async global_load_lds pipeline, restructured for 2 blocks/CU.
// v6 post-mortem: per-block path 490->315us (pipeline works) but LDS 97KB ->
// 1 block/CU -> 512 blocks ran as 2 serial rounds -> net regression.
// v7: 32-col staging chunks (A 8KB + B 16KB = 24KB/buffer), 3-buffer rotation
// (72KB) + sqj (1KB) = 74.75KB -> 2 blocks/CU restored. 2-deep prefetch:
// per step issue next-next chunk (6 loads), counted s_waitcnt vmcnt(12)
// (oldest 6 = current buffer landed; safe w/ older non-staging VMEM since
// FIFO only needs N <= #younger). 16 steps/js, 32 MFMA per step; K-order
// identical to v5/v6 -> bit-identical accumulation. Swizzle for 64B rows:
// seg ^ (row&3) on pre-swizzled global source AND ds_read (involution).
// Arithmetic identical to v5 (validated).
//
// Memory plan:
//   d_out: phase 1 holds cbt[f][2048][512] bf16 (32 MB); phase 2 holds
//          ct[f][2000][512] fp32 (exactly out_size floats); final gather output.
//   d_ws : sq 128KB + cand 2.56MB + dval 2.56MB + fidx 1MB ~= 6.3 MB.

#define F_TOT 2000
#define CF    16
#define KDIM  512
#define NB_K  8
#define IPAD  2048
#define NCAND 10
#define NCH   2
#define NCTOT (NCAND * NCH)

typedef __attribute__((ext_vector_type(8))) short bf16x8;
typedef __attribute__((ext_vector_type(4))) float f32x4;

__device__ inline unsigned short f2bf(float x) {
  unsigned int u = __float_as_uint(x);
  return (unsigned short)((u + 0x7fffu + ((u >> 16) & 1u)) >> 16);
}

// async 16B global -> LDS (LDS dest: wave-uniform base + lane*16)
#define GLOAD_LDS16(gp, lp)                                                          \
  __builtin_amdgcn_global_load_lds((const __attribute__((address_space(1))) void*)(gp), \
                                   (__attribute__((address_space(3))) void*)(lp), 16, 0, 0)

// ---------------------------------------------------------------- k1: sq (fp64)
// VALIDATED rounds 1-4 — do not change arithmetic.
__global__ __launch_bounds__(256) void sq_kernel(const float* __restrict__ coords,
                                                 float* __restrict__ sq_out) {
  int i = blockIdx.x;
  int t = threadIdx.x;
  int f = t & 15;
  int cg = t >> 4;
  const float* base = coords + (size_t)i * CF + f;
  double s = 0.0;
  for (int c = cg * 32; c < cg * 32 + 32; ++c) {
    float v = base[(size_t)c * (F_TOT * CF)];
    s += (double)v * (double)v;
  }
  __shared__ double red[256];
  red[t] = s;
  __syncthreads();
  if (cg == 0) {
    double tot = 0.0;
#pragma unroll
    for (int g = 0; g < 16; ++g) tot += red[g * 16 + f];
    sq_out[i * CF + f] = (float)tot;
  }
}

// ------------------------------------------- k2: coords -> cbt[f][i pad2048][c] bf16
__global__ __launch_bounds__(256) void cvt_bf16_kernel(const float* __restrict__ coords,
                                                       unsigned short* __restrict__ cbt) {
  __shared__ float lds[32 * 257];
  const int i0 = blockIdx.x * 16;    // 0..2032
  const int c0 = blockIdx.y * 32;
  const int t = threadIdx.x;
  const int io = t >> 4, f = t & 15;
  const int iclamp = min(i0 + io, F_TOT - 1);
  for (int cc = 0; cc < 32; ++cc)
    lds[cc * 257 + t] = coords[(size_t)(c0 + cc) * (F_TOT * CF) + iclamp * CF + f];
  __syncthreads();
  size_t obase = ((size_t)f * IPAD + (i0 + io)) * KDIM + c0;
#pragma unroll
  for (int cc = 0; cc < 32; cc += 4) {
    unsigned int lo = (unsigned int)f2bf(lds[(cc + 0) * 257 + t]) |
                      ((unsigned int)f2bf(lds[(cc + 1) * 257 + t]) << 16);
    unsigned int hi = (unsigned int)f2bf(lds[(cc + 2) * 257 + t]) |
                      ((unsigned int)f2bf(lds[(cc + 3) * 257 + t]) << 16);
    *(uint2*)(cbt + obase + cc) = make_uint2(lo, hi);
  }
}

// ------------------------------------------- k4: coords -> ct[f][i 2000][c] fp32
__global__ __launch_bounds__(256) void cvt_f32t_kernel(const float* __restrict__ coords,
                                                       float* __restrict__ ct) {
  __shared__ float lds[32 * 257];
  const int i0 = blockIdx.x * 16;    // 0..1984 (125 tiles exact)
  const int c0 = blockIdx.y * 32;
  const int t = threadIdx.x;
  const int io = t >> 4;
  for (int cc = 0; cc < 32; ++cc)
    lds[cc * 257 + t] = coords[(size_t)(c0 + cc) * (F_TOT * CF) + i0 * CF + t];
  __syncthreads();
  const int f = t & 15;
  size_t obase = ((size_t)f * F_TOT + (i0 + io)) * KDIM + c0;
#pragma unroll
  for (int cc = 0; cc < 32; cc += 4) {
    float4 v = make_float4(lds[(cc + 0) * 257 + t], lds[(cc + 1) * 257 + t],
                           lds[(cc + 2) * 257 + t], lds[(cc + 3) * 257 + t]);
    *(float4*)(ct + obase + cc) = v;
  }
}

// ------------------------------------------- k3: bf16 MFMA approx + top-10/chunk
// grid 512: f = bx&15, i-tile(128) = (bx>>4)&15, j-chunk(1000) = bx>>8.
// v7 staging: 32-col chunks, 3 x 24KB rotating buffers, 2-deep async prefetch.
// LDS slot s (16B units) <- global (row=s>>2, seg=(s&3)^(row&3)); phys slot
// (r,p) holds logical seg p^(r&3); fragment read applies the same XOR.
__global__ __launch_bounds__(256, 2) void approx_kernel(const unsigned short* __restrict__ cbt,
                                                        const float* __restrict__ sq,
                                                        int* __restrict__ cand) {
  const int bx = blockIdx.x;
  const int f = bx & 15;
  const int it = (bx >> 4) & 15;
  const int jc = bx >> 8;
  const int ibase = it * 128;
  const int jcbase = jc * 1000;
  const int jlimit = jcbase + 1000;

  const int t = threadIdx.x;
  const int lane = t & 63;
  const int w = t >> 6;
  const int wi = w & 1, wj = w >> 1;
  const int lrow = lane & 15, lq = lane >> 4;

  // buf q at q*24576: A [0,8192) = [128 rows][32 cols] bf16 (64B rows),
  //                   B [8192,24576) = [256 rows][32 cols] bf16.
  // Dl [128][128] f32 (64KB) aliases buf0+buf1+part of buf2 (staging idle then).
  // sqj at 73728.
  __shared__ char smem[74752];
  float* Dl = (float*)smem;
  float* sqj = (float*)(smem + 73728);

  const unsigned short* abase_g = cbt + ((size_t)f * IPAD + ibase) * KDIM;

  // scan identity: row ii, j-half (64 j per 128-j phase)
  const int ii = t & 127;
  const int half = t >> 7;
  const bool rowok = (ibase + ii < F_TOT);

  float bv[NCAND]; int bi[NCAND];
#pragma unroll
  for (int k = 0; k < NCAND; ++k) { bv[k] = __builtin_inff(); bi[k] = 0x7fffffff; }
  float sqi = rowok ? sq[(ibase + ii) * CF + f] : 0.0f;

  // A-fragment row geometry (per mi)
  int arow[4];
#pragma unroll
  for (int mi = 0; mi < 4; ++mi) arow[mi] = wi * 64 + mi * 16 + lrow;
  int brow[8];
#pragma unroll
  for (int nj = 0; nj < 8; ++nj) brow[nj] = wj * 128 + nj * 16 + lrow;

  for (int js = 0; js < 4; ++js) {
    const int jbase = jcbase + js * 256;
    __syncthreads();   // previous js's scan (Dl/sqj readers) done; staging may begin
    { int jg = jbase + t; sqj[t] = (jg < F_TOT) ? sq[jg * CF + f] : 0.0f; }

    f32x4 acc[4][8];
#pragma unroll
    for (int mi = 0; mi < 4; ++mi)
#pragma unroll
      for (int nj = 0; nj < 8; ++nj) acc[mi][nj] = (f32x4){0.f, 0.f, 0.f, 0.f};

    const unsigned short* bbase_g = cbt + ((size_t)f * IPAD + jbase) * KDIM;

    // stage one 32-col chunk (A: 2 instr, B: 4 instr) into buffer q.
    // source pre-swizzled: LDS slot s=(p*256+t) <- global (s>>2, (s&3)^((s>>2)&3))
#define STAGE32(q, c0)                                                                \
    {                                                                                 \
      char* Ad = smem + (q) * 24576;                                                  \
      char* Bd = Ad + 8192;                                                           \
      _Pragma("unroll")                                                               \
      for (int p = 0; p < 2; ++p) {                                                   \
        int s = p * 256 + t;                                                          \
        int r = s >> 2, sg = s & 3;                                                   \
        GLOAD_LDS16(abase_g + (size_t)r * KDIM + (c0) + ((sg ^ (r & 3)) << 3),        \
                    Ad + p * 4096 + (w << 10));                                       \
      }                                                                               \
      _Pragma("unroll")                                                               \
      for (int p = 0; p < 4; ++p) {                                                   \
        int s = p * 256 + t;                                                          \
        int r = s >> 2, sg = s & 3;                                                   \
        GLOAD_LDS16(bbase_g + (size_t)r * KDIM + (c0) + ((sg ^ (r & 3)) << 3),        \
                    Bd + p * 4096 + (w << 10));                                       \
      }                                                                               \
    }

    STAGE32(0, 0);                    // prologue: steps 0,1 in flight
    STAGE32(1, 32);

    for (int m = 0; m < 16; ++m) {
      const int cur = m % 3;
      const unsigned short* Al = (const unsigned short*)(smem + cur * 24576);
      const unsigned short* Bl = (const unsigned short*)(smem + cur * 24576 + 8192);
      // #1: all waves done reading the buffer about to be restaged (step m-1's)
      __builtin_amdgcn_s_barrier();
      if (m < 14) {
        STAGE32((m + 2) % 3, (m + 2) * 32);
        // wait the OLDEST 6 (current buffer); 12 younger stay in flight
        asm volatile("s_waitcnt vmcnt(12)" ::: "memory");
      } else if (m == 14) {
        asm volatile("s_waitcnt vmcnt(6)" ::: "memory");
      } else {
        asm volatile("s_waitcnt vmcnt(0)" ::: "memory");
      }
      // #2: every wave has waited its own loads -> buf[cur] fully populated
      __builtin_amdgcn_s_barrier();
      __builtin_amdgcn_sched_barrier(0);   // keep ds_reads below the fence
      bf16x8 a[4];
#pragma unroll
      for (int mi = 0; mi < 4; ++mi)
        a[mi] = *(const bf16x8*)(Al + arow[mi] * 32 + ((lq ^ (arow[mi] & 3)) << 3));
#pragma unroll
      for (int nj = 0; nj < 8; ++nj) {
        bf16x8 b = *(const bf16x8*)(Bl + brow[nj] * 32 + ((lq ^ (brow[nj] & 3)) << 3));
#pragma unroll
        for (int mi = 0; mi < 4; ++mi)
          acc[mi][nj] = __builtin_amdgcn_mfma_f32_16x16x32_bf16(a[mi], b, acc[mi][nj], 0, 0, 0);
      }
    }
#undef STAGE32

    // epilogue + scan: two phases of 128 j, all 256 threads scan
#pragma unroll
    for (int ph = 0; ph < 2; ++ph) {
      __syncthreads();
      if (wj == ph) {                          // these waves hold block-j [ph*128, +128)
#pragma unroll
        for (int mi = 0; mi < 4; ++mi) {
#pragma unroll
          for (int nj = 0; nj < 8; ++nj) {
#pragma unroll
            for (int r = 0; r < 4; ++r) {
              int row = wi * 64 + mi * 16 + lq * 4 + r;   // C: col=lane&15, row=quad*4+reg
              int col = nj * 16 + lrow;
              int q = col >> 2, rr = col & 3;
              Dl[row * 128 + (((q ^ (row & 7))) << 2) + rr] = acc[mi][nj][r];
            }
          }
        }
      }
      __syncthreads();
      if (rowok) {
        const int j0 = jbase + ph * 128 + half * 64;
        int cnt = jlimit - j0; if (cnt > 64) cnt = 64;
        for (int bb = 0; bb < 16; ++bb) {
          const int bo = bb * 4;
          if (bo >= cnt) break;
          const int qq = half * 16 + bb;
          const float4 g4 = *(const float4*)&Dl[ii * 128 + ((qq ^ (ii & 7)) << 2)];
          const float4 s4 = *(const float4*)&sqj[ph * 128 + half * 64 + bo];
          float d0 = fmaxf(fmaf(-2.0f, g4.x, sqi + s4.x), 0.0f);
          float d1 = fmaxf(fmaf(-2.0f, g4.y, sqi + s4.y), 0.0f);
          float d2 = fmaxf(fmaf(-2.0f, g4.z, sqi + s4.z), 0.0f);
          float d3 = fmaxf(fmaf(-2.0f, g4.w, sqi + s4.w), 0.0f);
          const int rem = cnt - bo;
          if (rem < 4) d3 = __builtin_inff();
          if (rem < 3) d2 = __builtin_inff();
          if (rem < 2) d1 = __builtin_inff();
          float mn = fminf(fminf(d0, d1), fminf(d2, d3));
          if (mn <= bv[NCAND - 1]) {           // gate; exact lex insert inside
            float dd[4] = {d0, d1, d2, d3};
#pragma unroll
            for (int e = 0; e < 4; ++e) {      // ascending j within the quad
              float d = dd[e]; int jg = j0 + bo + e;
              if (d < bv[NCAND - 1] || (d == bv[NCAND - 1] && jg < bi[NCAND - 1])) {
                float cv = d; int ci = jg;
#pragma unroll
                for (int k = 0; k < NCAND; ++k) {
                  bool lt = (cv < bv[k]) || (cv == bv[k] && ci < bi[k]);
                  float tv = lt ? bv[k] : cv; int ti = lt ? bi[k] : ci;
                  bv[k] = lt ? cv : bv[k];    bi[k] = lt ? ci : bi[k];
                  cv = tv; ci = ti;
                }
              }
            }
          }
        }
      }
    }
  }

  // merge the two j-half partial top-10s (lex-exact == chunk top-10)
  __syncthreads();
  if (half == 1 && rowok) {
    float* wrow = &Dl[ii * 128];
#pragma unroll
    for (int k = 0; k < NCAND; ++k) { wrow[k] = bv[k]; *(int*)&wrow[NCAND + k] = bi[k]; }
  }
  __syncthreads();
  if (half == 0 && rowok) {
    const float* wrow = &Dl[ii * 128];
    float ov[NCAND]; int oi[NCAND];
#pragma unroll
    for (int k = 0; k < NCAND; ++k) { ov[k] = wrow[k]; oi[k] = *(const int*)&wrow[NCAND + k]; }
    float mv[NCAND]; int mj[NCAND];
    int p = 0, q = 0;
#pragma unroll
    for (int k = 0; k < NCAND; ++k) {          // two-pointer lex merge, pick 10 smallest
      bool mine = (q >= NCAND) || ((p < NCAND) &&
                  ((bv[p] < ov[q]) || (bv[p] == ov[q] && bi[p] < oi[q])));
      mv[k] = mine ? bv[p] : ov[q];
      mj[k] = mine ? bi[p] : oi[q];
      p += mine ? 1 : 0; q += mine ? 0 : 1;
    }
    (void)mv;
    // sort the 10 candidate j's ascending (odd-even transposition)
#pragma unroll
    for (int r = 0; r < NCAND; ++r) {
#pragma unroll
      for (int k = 0; k + 1 < NCAND; ++k) {
        if (((k ^ r) & 1) == 0) {
          int lo = min(mj[k], mj[k + 1]);
          int hi = max(mj[k], mj[k + 1]);
          mj[k] = lo; mj[k + 1] = hi;
        }
      }
    }
    int* dst = cand + ((size_t)(ibase + ii) * CF + f) * NCTOT + jc * NCAND;
#pragma unroll
    for (int k = 0; k < NCAND; ++k) dst[k] = mj[k];
  }
}

// ------------------------------------------- k5: exact distances, 2 cands/thread
// VALIDATED arithmetic — ascending-c fmaf chain. 20 cands -> 10 pairs per (i,f).
__global__ __launch_bounds__(256) void refine_dist_kernel(const float* __restrict__ ct,
                                                          const float* __restrict__ sq,
                                                          const int* __restrict__ cand,
                                                          float* __restrict__ dval) {
  int x = blockIdx.x * 256 + threadIdx.x;    // 0..319999
  if (x >= F_TOT * CF * (NCTOT / 2)) return;
  int pf = x / (NCTOT / 2);
  int m = x - pf * (NCTOT / 2);
  int i = pf >> 4, f = pf & 15;
  const float* a = ct + ((size_t)f * F_TOT + i) * KDIM;
  float sqi = sq[i * CF + f];
  int j0 = cand[(size_t)pf * NCTOT + 2 * m];
  int j1 = cand[(size_t)pf * NCTOT + 2 * m + 1];
  const float* p = ct + ((size_t)f * F_TOT + j0) * KDIM;
  const float* q = ct + ((size_t)f * F_TOT + j1) * KDIM;
  float g0 = 0.0f, g1 = 0.0f;
  for (int c = 0; c < KDIM; c += 8) {
    float4 a0 = *(const float4*)(a + c), a1 = *(const float4*)(a + c + 4);
    float4 p0 = *(const float4*)(p + c), p1 = *(const float4*)(p + c + 4);
    float4 q0 = *(const float4*)(q + c), q1 = *(const float4*)(q + c + 4);
    g0 = fmaf(a0.x, p0.x, g0); g1 = fmaf(a0.x, q0.x, g1);
    g0 = fmaf(a0.y, p0.y, g0); g1 = fmaf(a0.y, q0.y, g1);
    g0 = fmaf(a0.z, p0.z, g0); g1 = fmaf(a0.z, q0.z, g1);
    g0 = fmaf(a0.w, p0.w, g0); g1 = fmaf(a0.w, q0.w, g1);
    g0 = fmaf(a1.x, p1.x, g0); g1 = fmaf(a1.x, q1.x, g1);
    g0 = fmaf(a1.y, p1.y, g0); g1 = fmaf(a1.y, q1.y, g1);
    g0 = fmaf(a1.z, p1.z, g0); g1 = fmaf(a1.z, q1.z, g1);
    g0 = fmaf(a1.w, p1.w, g0); g1 = fmaf(a1.w, q1.w, g1);
  }
  float d0 = fmaf(-2.0f, g0, sqi + sq[j0 * CF + f]); d0 = fmaxf(d0, 0.0f);
  float d1 = fmaf(-2.0f, g1, sqi + sq[j1 * CF + f]); d1 = fmaxf(d1, 0.0f);
  dval[(size_t)pf * NCTOT + 2 * m]     = d0;
  dval[(size_t)pf * NCTOT + 2 * m + 1] = d1;
}

// ------------------------------------------- k6: top-8 select (ascending-j, strict <)
__global__ __launch_bounds__(256) void select_kernel(const float* __restrict__ dval,
                                                     const int* __restrict__ cand,
                                                     int* __restrict__ fidx) {
  int pf = blockIdx.x * 256 + threadIdx.x;   // (i*16+f), 0..31999
  if (pf >= F_TOT * CF) return;
  int i = pf >> 4, f = pf & 15;
  float bval[NB_K]; int bidx[NB_K];
#pragma unroll
  for (int k = 0; k < NB_K; ++k) { bval[k] = __builtin_inff(); bidx[k] = 0; }
#pragma unroll
  for (int m = 0; m < NCTOT; ++m) {          // ascending j (chunks disjoint ascending)
    float d = dval[(size_t)pf * NCTOT + m];
    int j = cand[(size_t)pf * NCTOT + m];
    if (d < bval[NB_K - 1]) {
      float cv = d; int ci = j;
#pragma unroll
      for (int k = 0; k < NB_K; ++k)
        if (cv < bval[k]) {
          float tv = bval[k]; bval[k] = cv; cv = tv;
          int ti = bidx[k]; bidx[k] = ci; ci = ti;
        }
    }
  }
#pragma unroll
  for (int k = 0; k < NB_K; ++k)
    fidx[((size_t)i * NB_K + k) * CF + f] = bidx[k];
}

// ---------------------------------------------------------------- k7: gather
__global__ __launch_bounds__(256) void gather_kernel(const float* __restrict__ inputs,
                                                     const int* __restrict__ fidx,
                                                     float* __restrict__ out) {
  int b = blockIdx.y;
  int x = blockIdx.x * 256 + threadIdx.x;    // m*16+c
  int c = x & 15;
  int n = fidx[x];
  out[(size_t)b * (F_TOT * NB_K * CF) + x] =
      inputs[(size_t)b * (F_TOT * CF) + n * CF + c];
}

// ---------------------------------------------------------------- launcher
extern "C" void kernel_launch(void* const* d_in, const int* in_sizes, int n_in,
                              void* d_out, int out_size, void* d_ws, size_t ws_size,
                              hipStream_t stream) {
  const float* inputs = (const float*)d_in[0];   // (64, 2000, 16)
  const float* coords = (const float*)d_in[1];   // (512, 2000, 16)
  float* out = (float*)d_out;

  unsigned short* cbt = (unsigned short*)d_out;  // 16*2048*512 bf16 (phase 1)
  float* ct = (float*)d_out;                     // 16*2000*512 f32 (phase 2, == out_size)

  float* sq = (float*)d_ws;                      // 32768 floats
  int* cand = (int*)d_ws + 32768;                // 32000*20 ints
  float* dval = (float*)d_ws + 32768 + 32000 * NCTOT; // 32000*20 floats
  int* fidx = (int*)d_ws + 32768 + 2 * 32000 * NCTOT; // 256000 ints

  sq_kernel<<<F_TOT, 256, 0, stream>>>(coords, sq);
  cvt_bf16_kernel<<<dim3(IPAD / 16, KDIM / 32), 256, 0, stream>>>(coords, cbt);
  approx_kernel<<<512, 256, 0, stream>>>(cbt, sq, cand);
  cvt_f32t_kernel<<<dim3(F_TOT / 16, KDIM / 32), 256, 0, stream>>>(coords, ct);
  refine_dist_kernel<<<(F_TOT * CF * (NCTOT / 2) + 255) / 256, 256, 0, stream>>>(ct, sq, cand, dval);
  select_kernel<<<(F_TOT * CF + 255) / 256, 256, 0, stream>>>(dval, cand, fidx);
  dim3 g7((F_TOT * NB_K * CF) / 256, 64);
  gather_kernel<<<g7, 256, 0, stream>>>(inputs, fidx, out);
}

// Round 3
// 833.882 us; speedup vs baseline: 1.2872x; 1.0539x over previous
//
#include <hip/hip_runtime.h>
#include <math.h>

// PhyloNeighbours: per-filter (16) kNN (k=8) over 2000 features, 512-dim coords.
// v8 = v7 + refine_dist locality fix.
// v7 post-mortem: approx 433us, but total 879 -> the OTHER kernels sum to
// ~446us. Floors for sq/cvt/select/gather ~= 90us => refine_dist ~= 350us.
// Cause: refine gathers 20 cand rows x 2KB per (i,f) = 1.34GB; ct (64MB) >>
// 4MB XCD L2 and the i-major mapping makes every block touch all 16 f-panels
// -> all reads from L3. v8: f-major thread mapping (x = f*20000 + i*10 + m)
// + bijective XCD-chunked block swizzle (q=156,r=2 over 1250 blocks) so each
// XCD's resident blocks cover ~2 contiguous 4MB panels -> candidate rows go
// L2-resident (~10x per-row reuse). Same per-(i,f,m) arithmetic and same
// dval/cand layout -> bit-identical output.
// approx kernel unchanged from v7 (async 3-buffer global_load_lds pipeline,
// 2 blocks/CU, counted vmcnt(12)).
//
// Memory plan:
//   d_out: phase 1 holds cbt[f][2048][512] bf16 (32 MB); phase 2 holds
//          ct[f][2000][512] fp32 (exactly out_size floats); final gather output.
//   d_ws : sq 128KB + cand 2.56MB + dval 2.56MB + fidx 1MB ~= 6.3 MB.

#define F_TOT 2000
#define CF    16
#define KDIM  512
#define NB_K  8
#define IPAD  2048
#define NCAND 10
#define NCH   2
#define NCTOT (NCAND * NCH)

typedef __attribute__((ext_vector_type(8))) short bf16x8;
typedef __attribute__((ext_vector_type(4))) float f32x4;

__device__ inline unsigned short f2bf(float x) {
  unsigned int u = __float_as_uint(x);
  return (unsigned short)((u + 0x7fffu + ((u >> 16) & 1u)) >> 16);
}

// async 16B global -> LDS (LDS dest: wave-uniform base + lane*16)
#define GLOAD_LDS16(gp, lp)                                                          \
  __builtin_amdgcn_global_load_lds((const __attribute__((address_space(1))) void*)(gp), \
                                   (__attribute__((address_space(3))) void*)(lp), 16, 0, 0)

// ---------------------------------------------------------------- k1: sq (fp64)
// VALIDATED rounds 1-4 — do not change arithmetic.
__global__ __launch_bounds__(256) void sq_kernel(const float* __restrict__ coords,
                                                 float* __restrict__ sq_out) {
  int i = blockIdx.x;
  int t = threadIdx.x;
  int f = t & 15;
  int cg = t >> 4;
  const float* base = coords + (size_t)i * CF + f;
  double s = 0.0;
  for (int c = cg * 32; c < cg * 32 + 32; ++c) {
    float v = base[(size_t)c * (F_TOT * CF)];
    s += (double)v * (double)v;
  }
  __shared__ double red[256];
  red[t] = s;
  __syncthreads();
  if (cg == 0) {
    double tot = 0.0;
#pragma unroll
    for (int g = 0; g < 16; ++g) tot += red[g * 16 + f];
    sq_out[i * CF + f] = (float)tot;
  }
}

// ------------------------------------------- k2: coords -> cbt[f][i pad2048][c] bf16
__global__ __launch_bounds__(256) void cvt_bf16_kernel(const float* __restrict__ coords,
                                                       unsigned short* __restrict__ cbt) {
  __shared__ float lds[32 * 257];
  const int i0 = blockIdx.x * 16;    // 0..2032
  const int c0 = blockIdx.y * 32;
  const int t = threadIdx.x;
  const int io = t >> 4, f = t & 15;
  const int iclamp = min(i0 + io, F_TOT - 1);
  for (int cc = 0; cc < 32; ++cc)
    lds[cc * 257 + t] = coords[(size_t)(c0 + cc) * (F_TOT * CF) + iclamp * CF + f];
  __syncthreads();
  size_t obase = ((size_t)f * IPAD + (i0 + io)) * KDIM + c0;
#pragma unroll
  for (int cc = 0; cc < 32; cc += 4) {
    unsigned int lo = (unsigned int)f2bf(lds[(cc + 0) * 257 + t]) |
                      ((unsigned int)f2bf(lds[(cc + 1) * 257 + t]) << 16);
    unsigned int hi = (unsigned int)f2bf(lds[(cc + 2) * 257 + t]) |
                      ((unsigned int)f2bf(lds[(cc + 3) * 257 + t]) << 16);
    *(uint2*)(cbt + obase + cc) = make_uint2(lo, hi);
  }
}

// ------------------------------------------- k4: coords -> ct[f][i 2000][c] fp32
__global__ __launch_bounds__(256) void cvt_f32t_kernel(const float* __restrict__ coords,
                                                       float* __restrict__ ct) {
  __shared__ float lds[32 * 257];
  const int i0 = blockIdx.x * 16;    // 0..1984 (125 tiles exact)
  const int c0 = blockIdx.y * 32;
  const int t = threadIdx.x;
  const int io = t >> 4;
  for (int cc = 0; cc < 32; ++cc)
    lds[cc * 257 + t] = coords[(size_t)(c0 + cc) * (F_TOT * CF) + i0 * CF + t];
  __syncthreads();
  const int f = t & 15;
  size_t obase = ((size_t)f * F_TOT + (i0 + io)) * KDIM + c0;
#pragma unroll
  for (int cc = 0; cc < 32; cc += 4) {
    float4 v = make_float4(lds[(cc + 0) * 257 + t], lds[(cc + 1) * 257 + t],
                           lds[(cc + 2) * 257 + t], lds[(cc + 3) * 257 + t]);
    *(float4*)(ct + obase + cc) = v;
  }
}

// ------------------------------------------- k3: bf16 MFMA approx + top-10/chunk
// grid 512: f = bx&15, i-tile(128) = (bx>>4)&15, j-chunk(1000) = bx>>8.
// v7 staging: 32-col chunks, 3 x 24KB rotating buffers, 2-deep async prefetch.
// LDS slot s (16B units) <- global (row=s>>2, seg=(s&3)^(row&3)); phys slot
// (r,p) holds logical seg p^(r&3); fragment read applies the same XOR.
__global__ __launch_bounds__(256, 2) void approx_kernel(const unsigned short* __restrict__ cbt,
                                                        const float* __restrict__ sq,
                                                        int* __restrict__ cand) {
  const int bx = blockIdx.x;
  const int f = bx & 15;
  const int it = (bx >> 4) & 15;
  const int jc = bx >> 8;
  const int ibase = it * 128;
  const int jcbase = jc * 1000;
  const int jlimit = jcbase + 1000;

  const int t = threadIdx.x;
  const int lane = t & 63;
  const int w = t >> 6;
  const int wi = w & 1, wj = w >> 1;
  const int lrow = lane & 15, lq = lane >> 4;

  // buf q at q*24576: A [0,8192) = [128 rows][32 cols] bf16 (64B rows),
  //                   B [8192,24576) = [256 rows][32 cols] bf16.
  // Dl [128][128] f32 (64KB) aliases buf0+buf1+part of buf2 (staging idle then).
  // sqj at 73728.
  __shared__ char smem[74752];
  float* Dl = (float*)smem;
  float* sqj = (float*)(smem + 73728);

  const unsigned short* abase_g = cbt + ((size_t)f * IPAD + ibase) * KDIM;

  // scan identity: row ii, j-half (64 j per 128-j phase)
  const int ii = t & 127;
  const int half = t >> 7;
  const bool rowok = (ibase + ii < F_TOT);

  float bv[NCAND]; int bi[NCAND];
#pragma unroll
  for (int k = 0; k < NCAND; ++k) { bv[k] = __builtin_inff(); bi[k] = 0x7fffffff; }
  float sqi = rowok ? sq[(ibase + ii) * CF + f] : 0.0f;

  // A-fragment row geometry (per mi)
  int arow[4];
#pragma unroll
  for (int mi = 0; mi < 4; ++mi) arow[mi] = wi * 64 + mi * 16 + lrow;
  int brow[8];
#pragma unroll
  for (int nj = 0; nj < 8; ++nj) brow[nj] = wj * 128 + nj * 16 + lrow;

  for (int js = 0; js < 4; ++js) {
    const int jbase = jcbase + js * 256;
    __syncthreads();   // previous js's scan (Dl/sqj readers) done; staging may begin
    { int jg = jbase + t; sqj[t] = (jg < F_TOT) ? sq[jg * CF + f] : 0.0f; }

    f32x4 acc[4][8];
#pragma unroll
    for (int mi = 0; mi < 4; ++mi)
#pragma unroll
      for (int nj = 0; nj < 8; ++nj) acc[mi][nj] = (f32x4){0.f, 0.f, 0.f, 0.f};

    const unsigned short* bbase_g = cbt + ((size_t)f * IPAD + jbase) * KDIM;

    // stage one 32-col chunk (A: 2 instr, B: 4 instr) into buffer q.
    // source pre-swizzled: LDS slot s=(p*256+t) <- global (s>>2, (s&3)^((s>>2)&3))
#define STAGE32(q, c0)                                                                \
    {                                                                                 \
      char* Ad = smem + (q) * 24576;                                                  \
      char* Bd = Ad + 8192;                                                           \
      _Pragma("unroll")                                                               \
      for (int p = 0; p < 2; ++p) {                                                   \
        int s = p * 256 + t;                                                          \
        int r = s >> 2, sg = s & 3;                                                   \
        GLOAD_LDS16(abase_g + (size_t)r * KDIM + (c0) + ((sg ^ (r & 3)) << 3),        \
                    Ad + p * 4096 + (w << 10));                                       \
      }                                                                               \
      _Pragma("unroll")                                                               \
      for (int p = 0; p < 4; ++p) {                                                   \
        int s = p * 256 + t;                                                          \
        int r = s >> 2, sg = s & 3;                                                   \
        GLOAD_LDS16(bbase_g + (size_t)r * KDIM + (c0) + ((sg ^ (r & 3)) << 3),        \
                    Bd + p * 4096 + (w << 10));                                       \
      }                                                                               \
    }

    STAGE32(0, 0);                    // prologue: steps 0,1 in flight
    STAGE32(1, 32);

    for (int m = 0; m < 16; ++m) {
      const int cur = m % 3;
      const unsigned short* Al = (const unsigned short*)(smem + cur * 24576);
      const unsigned short* Bl = (const unsigned short*)(smem + cur * 24576 + 8192);
      // #1: all waves done reading the buffer about to be restaged (step m-1's)
      __builtin_amdgcn_s_barrier();
      if (m < 14) {
        STAGE32((m + 2) % 3, (m + 2) * 32);
        // wait the OLDEST 6 (current buffer); 12 younger stay in flight
        asm volatile("s_waitcnt vmcnt(12)" ::: "memory");
      } else if (m == 14) {
        asm volatile("s_waitcnt vmcnt(6)" ::: "memory");
      } else {
        asm volatile("s_waitcnt vmcnt(0)" ::: "memory");
      }
      // #2: every wave has waited its own loads -> buf[cur] fully populated
      __builtin_amdgcn_s_barrier();
      __builtin_amdgcn_sched_barrier(0);   // keep ds_reads below the fence
      bf16x8 a[4];
#pragma unroll
      for (int mi = 0; mi < 4; ++mi)
        a[mi] = *(const bf16x8*)(Al + arow[mi] * 32 + ((lq ^ (arow[mi] & 3)) << 3));
#pragma unroll
      for (int nj = 0; nj < 8; ++nj) {
        bf16x8 b = *(const bf16x8*)(Bl + brow[nj] * 32 + ((lq ^ (brow[nj] & 3)) << 3));
#pragma unroll
        for (int mi = 0; mi < 4; ++mi)
          acc[mi][nj] = __builtin_amdgcn_mfma_f32_16x16x32_bf16(a[mi], b, acc[mi][nj], 0, 0, 0);
      }
    }
#undef STAGE32

    // epilogue + scan: two phases of 128 j, all 256 threads scan
#pragma unroll
    for (int ph = 0; ph < 2; ++ph) {
      __syncthreads();
      if (wj == ph) {                          // these waves hold block-j [ph*128, +128)
#pragma unroll
        for (int mi = 0; mi < 4; ++mi) {
#pragma unroll
          for (int nj = 0; nj < 8; ++nj) {
#pragma unroll
            for (int r = 0; r < 4; ++r) {
              int row = wi * 64 + mi * 16 + lq * 4 + r;   // C: col=lane&15, row=quad*4+reg
              int col = nj * 16 + lrow;
              int q = col >> 2, rr = col & 3;
              Dl[row * 128 + (((q ^ (row & 7))) << 2) + rr] = acc[mi][nj][r];
            }
          }
        }
      }
      __syncthreads();
      if (rowok) {
        const int j0 = jbase + ph * 128 + half * 64;
        int cnt = jlimit - j0; if (cnt > 64) cnt = 64;
        for (int bb = 0; bb < 16; ++bb) {
          const int bo = bb * 4;
          if (bo >= cnt) break;
          const int qq = half * 16 + bb;
          const float4 g4 = *(const float4*)&Dl[ii * 128 + ((qq ^ (ii & 7)) << 2)];
          const float4 s4 = *(const float4*)&sqj[ph * 128 + half * 64 + bo];
          float d0 = fmaxf(fmaf(-2.0f, g4.x, sqi + s4.x), 0.0f);
          float d1 = fmaxf(fmaf(-2.0f, g4.y, sqi + s4.y), 0.0f);
          float d2 = fmaxf(fmaf(-2.0f, g4.z, sqi + s4.z), 0.0f);
          float d3 = fmaxf(fmaf(-2.0f, g4.w, sqi + s4.w), 0.0f);
          const int rem = cnt - bo;
          if (rem < 4) d3 = __builtin_inff();
          if (rem < 3) d2 = __builtin_inff();
          if (rem < 2) d1 = __builtin_inff();
          float mn = fminf(fminf(d0, d1), fminf(d2, d3));
          if (mn <= bv[NCAND - 1]) {           // gate; exact lex insert inside
            float dd[4] = {d0, d1, d2, d3};
#pragma unroll
            for (int e = 0; e < 4; ++e) {      // ascending j within the quad
              float d = dd[e]; int jg = j0 + bo + e;
              if (d < bv[NCAND - 1] || (d == bv[NCAND - 1] && jg < bi[NCAND - 1])) {
                float cv = d; int ci = jg;
#pragma unroll
                for (int k = 0; k < NCAND; ++k) {
                  bool lt = (cv < bv[k]) || (cv == bv[k] && ci < bi[k]);
                  float tv = lt ? bv[k] : cv; int ti = lt ? bi[k] : ci;
                  bv[k] = lt ? cv : bv[k];    bi[k] = lt ? ci : bi[k];
                  cv = tv; ci = ti;
                }
              }
            }
          }
        }
      }
    }
  }

  // merge the two j-half partial top-10s (lex-exact == chunk top-10)
  __syncthreads();
  if (half == 1 && rowok) {
    float* wrow = &Dl[ii * 128];
#pragma unroll
    for (int k = 0; k < NCAND; ++k) { wrow[k] = bv[k]; *(int*)&wrow[NCAND + k] = bi[k]; }
  }
  __syncthreads();
  if (half == 0 && rowok) {
    const float* wrow = &Dl[ii * 128];
    float ov[NCAND]; int oi[NCAND];
#pragma unroll
    for (int k = 0; k < NCAND; ++k) { ov[k] = wrow[k]; oi[k] = *(const int*)&wrow[NCAND + k]; }
    float mv[NCAND]; int mj[NCAND];
    int p = 0, q = 0;
#pragma unroll
    for (int k = 0; k < NCAND; ++k) {          // two-pointer lex merge, pick 10 smallest
      bool mine = (q >= NCAND) || ((p < NCAND) &&
                  ((bv[p] < ov[q]) || (bv[p] == ov[q] && bi[p] < oi[q])));
      mv[k] = mine ? bv[p] : ov[q];
      mj[k] = mine ? bi[p] : oi[q];
      p += mine ? 1 : 0; q += mine ? 0 : 1;
    }
    (void)mv;
    // sort the 10 candidate j's ascending (odd-even transposition)
#pragma unroll
    for (int r = 0; r < NCAND; ++r) {
#pragma unroll
      for (int k = 0; k + 1 < NCAND; ++k) {
        if (((k ^ r) & 1) == 0) {
          int lo = min(mj[k], mj[k + 1]);
          int hi = max(mj[k], mj[k + 1]);
          mj[k] = lo; mj[k + 1] = hi;
        }
      }
    }
    int* dst = cand + ((size_t)(ibase + ii) * CF + f) * NCTOT + jc * NCAND;
#pragma unroll
    for (int k = 0; k < NCAND; ++k) dst[k] = mj[k];
  }
}

// ------------------------------------------- k5: exact distances, 2 cands/thread
// VALIDATED arithmetic — ascending-c fmaf chain. 20 cands -> 10 pairs per (i,f).
// v8: f-major thread mapping + bijective XCD-chunked block swizzle so each
// XCD's resident blocks read candidate rows from ~2 contiguous f-panels
// (L2-resident) instead of all 16 (L3). Same per-(i,f,m) work and same
// dval/cand memory layout -> bit-identical output.
__global__ __launch_bounds__(256) void refine_dist_kernel(const float* __restrict__ ct,
                                                          const float* __restrict__ sq,
                                                          const int* __restrict__ cand,
                                                          float* __restrict__ dval) {
  const int NTH = F_TOT * CF * (NCTOT / 2);      // 320000
  const int NWG = (NTH + 255) / 256;             // 1250
  const int qch = NWG >> 3, rch = NWG & 7;       // 156, 2
  int orig = blockIdx.x;
  int xcd = orig & 7, idx = orig >> 3;
  int bid = (xcd < rch ? xcd * (qch + 1) : rch * (qch + 1) + (xcd - rch) * qch) + idx;
  int x = bid * 256 + threadIdx.x;
  if (x >= NTH) return;
  // f-major: x = f*(2000*10) + i*10 + m
  int f = x / (F_TOT * (NCTOT / 2));
  int y = x - f * (F_TOT * (NCTOT / 2));
  int i = y / (NCTOT / 2);
  int m = y - i * (NCTOT / 2);
  int pf = i * CF + f;
  const float* a = ct + ((size_t)f * F_TOT + i) * KDIM;
  float sqi = sq[i * CF + f];
  int j0 = cand[(size_t)pf * NCTOT + 2 * m];
  int j1 = cand[(size_t)pf * NCTOT + 2 * m + 1];
  const float* p = ct + ((size_t)f * F_TOT + j0) * KDIM;
  const float* q = ct + ((size_t)f * F_TOT + j1) * KDIM;
  float g0 = 0.0f, g1 = 0.0f;
  for (int c = 0; c < KDIM; c += 8) {
    float4 a0 = *(const float4*)(a + c), a1 = *(const float4*)(a + c + 4);
    float4 p0 = *(const float4*)(p + c), p1 = *(const float4*)(p + c + 4);
    float4 q0 = *(const float4*)(q + c), q1 = *(const float4*)(q + c + 4);
    g0 = fmaf(a0.x, p0.x, g0); g1 = fmaf(a0.x, q0.x, g1);
    g0 = fmaf(a0.y, p0.y, g0); g1 = fmaf(a0.y, q0.y, g1);
    g0 = fmaf(a0.z, p0.z, g0); g1 = fmaf(a0.z, q0.z, g1);
    g0 = fmaf(a0.w, p0.w, g0); g1 = fmaf(a0.w, q0.w, g1);
    g0 = fmaf(a1.x, p1.x, g0); g1 = fmaf(a1.x, q1.x, g1);
    g0 = fmaf(a1.y, p1.y, g0); g1 = fmaf(a1.y, q1.y, g1);
    g0 = fmaf(a1.z, p1.z, g0); g1 = fmaf(a1.z, q1.z, g1);
    g0 = fmaf(a1.w, p1.w, g0); g1 = fmaf(a1.w, q1.w, g1);
  }
  float d0 = fmaf(-2.0f, g0, sqi + sq[j0 * CF + f]); d0 = fmaxf(d0, 0.0f);
  float d1 = fmaf(-2.0f, g1, sqi + sq[j1 * CF + f]); d1 = fmaxf(d1, 0.0f);
  dval[(size_t)pf * NCTOT + 2 * m]     = d0;
  dval[(size_t)pf * NCTOT + 2 * m + 1] = d1;
}

// ------------------------------------------- k6: top-8 select (ascending-j, strict <)
__global__ __launch_bounds__(256) void select_kernel(const float* __restrict__ dval,
                                                     const int* __restrict__ cand,
                                                     int* __restrict__ fidx) {
  int pf = blockIdx.x * 256 + threadIdx.x;   // (i*16+f), 0..31999
  if (pf >= F_TOT * CF) return;
  int i = pf >> 4, f = pf & 15;
  float bval[NB_K]; int bidx[NB_K];
#pragma unroll
  for (int k = 0; k < NB_K; ++k) { bval[k] = __builtin_inff(); bidx[k] = 0; }
#pragma unroll
  for (int m = 0; m < NCTOT; ++m) {          // ascending j (chunks disjoint ascending)
    float d = dval[(size_t)pf * NCTOT + m];
    int j = cand[(size_t)pf * NCTOT + m];
    if (d < bval[NB_K - 1]) {
      float cv = d; int ci = j;
#pragma unroll
      for (int k = 0; k < NB_K; ++k)
        if (cv < bval[k]) {
          float tv = bval[k]; bval[k] = cv; cv = tv;
          int ti = bidx[k]; bidx[k] = ci; ci = ti;
        }
    }
  }
#pragma unroll
  for (int k = 0; k < NB_K; ++k)
    fidx[((size_t)i * NB_K + k) * CF + f] = bidx[k];
}

// ---------------------------------------------------------------- k7: gather
__global__ __launch_bounds__(256) void gather_kernel(const float* __restrict__ inputs,
                                                     const int* __restrict__ fidx,
                                                     float* __restrict__ out) {
  int b = blockIdx.y;
  int x = blockIdx.x * 256 + threadIdx.x;    // m*16+c
  int c = x & 15;
  int n = fidx[x];
  out[(size_t)b * (F_TOT * NB_K * CF) + x] =
      inputs[(size_t)b * (F_TOT * CF) + n * CF + c];
}

// ---------------------------------------------------------------- launcher
extern "C" void kernel_launch(void* const* d_in, const int* in_sizes, int n_in,
                              void* d_out, int out_size, void* d_ws, size_t ws_size,
                              hipStream_t stream) {
  const float* inputs = (const float*)d_in[0];   // (64, 2000, 16)
  const float* coords = (const float*)d_in[1];   // (512, 2000, 16)
  float* out = (float*)d_out;

  unsigned short* cbt = (unsigned short*)d_out;  // 16*2048*512 bf16 (phase 1)
  float* ct = (float*)d_out;                     // 16*2000*512 f32 (phase 2, == out_size)

  float* sq = (float*)d_ws;                      // 32768 floats
  int* cand = (int*)d_ws + 32768;                // 32000*20 ints
  float* dval = (float*)d_ws + 32768 + 32000 * NCTOT; // 32000*20 floats
  int* fidx = (int*)d_ws + 32768 + 2 * 32000 * NCTOT; // 256000 ints

  sq_kernel<<<F_TOT, 256, 0, stream>>>(coords, sq);
  cvt_bf16_kernel<<<dim3(IPAD / 16, KDIM / 32), 256, 0, stream>>>(coords, cbt);
  approx_kernel<<<512, 256, 0, stream>>>(cbt, sq, cand);
  cvt_f32t_kernel<<<dim3(F_TOT / 16, KDIM / 32), 256, 0, stream>>>(coords, ct);
  refine_dist_kernel<<<(F_TOT * CF * (NCTOT / 2) + 255) / 256, 256, 0, stream>>>(ct, sq, cand, dval);
  select_kernel<<<(F_TOT * CF + 255) / 256, 256, 0, stream>>>(dval, cand, fidx);
  dim3 g7((F_TOT * NB_K * CF) / 256, 64);
  gather_kernel<<<g7, 256, 0, stream>>>(inputs, fidx, out);
}

// Round 4
// 717.993 us; speedup vs baseline: 1.4950x; 1.1614x over previous
//
#include <hip/hip_runtime.h>
#include <math.h>

// PhyloNeighbours: per-filter (16) kNN (k=8) over 2000 features, 512-dim coords.
// v9 = v8 + wave-cooperative refine_dist.
// v8 post-mortem: f-major + XCD swizzle gained only 45us (predicted 250) ->
// refine is NOT locality-bound; it is scatter-REQUEST-bound: 64 lanes/wave
// stream 64 different rows -> 64 distinct cachelines per load instr, 16B
// used per line-request; TA/TCP request rate is the floor (~270us).
// v9: 8 lanes cooperate per candidate-pair. Lane k reads row+n*128+k*16 ->
// one fully-used 128B line per 8 lanes, 8 lines/instr per wave (8x fewer
// requests). Per-lane ascending-c fmaf sub-chains + 3-step shfl_xor butterfly;
// lane 0 applies validated d = fmaf(-2,g,sqi+sqj), clamp, store. dval/cand
// layout and select logic unchanged. (Reassociates the f32 dot sum; ranking
// margins >> 1e-5 rounding noise — reference and v8 already used two
// different f32 orders and agreed exactly on indices.)
// approx kernel unchanged from v7 (async 3-buffer global_load_lds pipeline,
// 2 blocks/CU, counted vmcnt(12)).
//
// Memory plan:
//   d_out: phase 1 holds cbt[f][2048][512] bf16 (32 MB); phase 2 holds
//          ct[f][2000][512] fp32 (exactly out_size floats); final gather output.
//   d_ws : sq 128KB + cand 2.56MB + dval 2.56MB + fidx 1MB ~= 6.3 MB.

#define F_TOT 2000
#define CF    16
#define KDIM  512
#define NB_K  8
#define IPAD  2048
#define NCAND 10
#define NCH   2
#define NCTOT (NCAND * NCH)

typedef __attribute__((ext_vector_type(8))) short bf16x8;
typedef __attribute__((ext_vector_type(4))) float f32x4;

__device__ inline unsigned short f2bf(float x) {
  unsigned int u = __float_as_uint(x);
  return (unsigned short)((u + 0x7fffu + ((u >> 16) & 1u)) >> 16);
}

// async 16B global -> LDS (LDS dest: wave-uniform base + lane*16)
#define GLOAD_LDS16(gp, lp)                                                          \
  __builtin_amdgcn_global_load_lds((const __attribute__((address_space(1))) void*)(gp), \
                                   (__attribute__((address_space(3))) void*)(lp), 16, 0, 0)

// ---------------------------------------------------------------- k1: sq (fp64)
// VALIDATED rounds 1-4 — do not change arithmetic.
__global__ __launch_bounds__(256) void sq_kernel(const float* __restrict__ coords,
                                                 float* __restrict__ sq_out) {
  int i = blockIdx.x;
  int t = threadIdx.x;
  int f = t & 15;
  int cg = t >> 4;
  const float* base = coords + (size_t)i * CF + f;
  double s = 0.0;
  for (int c = cg * 32; c < cg * 32 + 32; ++c) {
    float v = base[(size_t)c * (F_TOT * CF)];
    s += (double)v * (double)v;
  }
  __shared__ double red[256];
  red[t] = s;
  __syncthreads();
  if (cg == 0) {
    double tot = 0.0;
#pragma unroll
    for (int g = 0; g < 16; ++g) tot += red[g * 16 + f];
    sq_out[i * CF + f] = (float)tot;
  }
}

// ------------------------------------------- k2: coords -> cbt[f][i pad2048][c] bf16
__global__ __launch_bounds__(256) void cvt_bf16_kernel(const float* __restrict__ coords,
                                                       unsigned short* __restrict__ cbt) {
  __shared__ float lds[32 * 257];
  const int i0 = blockIdx.x * 16;    // 0..2032
  const int c0 = blockIdx.y * 32;
  const int t = threadIdx.x;
  const int io = t >> 4, f = t & 15;
  const int iclamp = min(i0 + io, F_TOT - 1);
  for (int cc = 0; cc < 32; ++cc)
    lds[cc * 257 + t] = coords[(size_t)(c0 + cc) * (F_TOT * CF) + iclamp * CF + f];
  __syncthreads();
  size_t obase = ((size_t)f * IPAD + (i0 + io)) * KDIM + c0;
#pragma unroll
  for (int cc = 0; cc < 32; cc += 4) {
    unsigned int lo = (unsigned int)f2bf(lds[(cc + 0) * 257 + t]) |
                      ((unsigned int)f2bf(lds[(cc + 1) * 257 + t]) << 16);
    unsigned int hi = (unsigned int)f2bf(lds[(cc + 2) * 257 + t]) |
                      ((unsigned int)f2bf(lds[(cc + 3) * 257 + t]) << 16);
    *(uint2*)(cbt + obase + cc) = make_uint2(lo, hi);
  }
}

// ------------------------------------------- k4: coords -> ct[f][i 2000][c] fp32
__global__ __launch_bounds__(256) void cvt_f32t_kernel(const float* __restrict__ coords,
                                                       float* __restrict__ ct) {
  __shared__ float lds[32 * 257];
  const int i0 = blockIdx.x * 16;    // 0..1984 (125 tiles exact)
  const int c0 = blockIdx.y * 32;
  const int t = threadIdx.x;
  const int io = t >> 4;
  for (int cc = 0; cc < 32; ++cc)
    lds[cc * 257 + t] = coords[(size_t)(c0 + cc) * (F_TOT * CF) + i0 * CF + t];
  __syncthreads();
  const int f = t & 15;
  size_t obase = ((size_t)f * F_TOT + (i0 + io)) * KDIM + c0;
#pragma unroll
  for (int cc = 0; cc < 32; cc += 4) {
    float4 v = make_float4(lds[(cc + 0) * 257 + t], lds[(cc + 1) * 257 + t],
                           lds[(cc + 2) * 257 + t], lds[(cc + 3) * 257 + t]);
    *(float4*)(ct + obase + cc) = v;
  }
}

// ------------------------------------------- k3: bf16 MFMA approx + top-10/chunk
// grid 512: f = bx&15, i-tile(128) = (bx>>4)&15, j-chunk(1000) = bx>>8.
// v7 staging: 32-col chunks, 3 x 24KB rotating buffers, 2-deep async prefetch.
// LDS slot s (16B units) <- global (row=s>>2, seg=(s&3)^(row&3)); phys slot
// (r,p) holds logical seg p^(r&3); fragment read applies the same XOR.
__global__ __launch_bounds__(256, 2) void approx_kernel(const unsigned short* __restrict__ cbt,
                                                        const float* __restrict__ sq,
                                                        int* __restrict__ cand) {
  const int bx = blockIdx.x;
  const int f = bx & 15;
  const int it = (bx >> 4) & 15;
  const int jc = bx >> 8;
  const int ibase = it * 128;
  const int jcbase = jc * 1000;
  const int jlimit = jcbase + 1000;

  const int t = threadIdx.x;
  const int lane = t & 63;
  const int w = t >> 6;
  const int wi = w & 1, wj = w >> 1;
  const int lrow = lane & 15, lq = lane >> 4;

  // buf q at q*24576: A [0,8192) = [128 rows][32 cols] bf16 (64B rows),
  //                   B [8192,24576) = [256 rows][32 cols] bf16.
  // Dl [128][128] f32 (64KB) aliases buf0+buf1+part of buf2 (staging idle then).
  // sqj at 73728.
  __shared__ char smem[74752];
  float* Dl = (float*)smem;
  float* sqj = (float*)(smem + 73728);

  const unsigned short* abase_g = cbt + ((size_t)f * IPAD + ibase) * KDIM;

  // scan identity: row ii, j-half (64 j per 128-j phase)
  const int ii = t & 127;
  const int half = t >> 7;
  const bool rowok = (ibase + ii < F_TOT);

  float bv[NCAND]; int bi[NCAND];
#pragma unroll
  for (int k = 0; k < NCAND; ++k) { bv[k] = __builtin_inff(); bi[k] = 0x7fffffff; }
  float sqi = rowok ? sq[(ibase + ii) * CF + f] : 0.0f;

  // A-fragment row geometry (per mi)
  int arow[4];
#pragma unroll
  for (int mi = 0; mi < 4; ++mi) arow[mi] = wi * 64 + mi * 16 + lrow;
  int brow[8];
#pragma unroll
  for (int nj = 0; nj < 8; ++nj) brow[nj] = wj * 128 + nj * 16 + lrow;

  for (int js = 0; js < 4; ++js) {
    const int jbase = jcbase + js * 256;
    __syncthreads();   // previous js's scan (Dl/sqj readers) done; staging may begin
    { int jg = jbase + t; sqj[t] = (jg < F_TOT) ? sq[jg * CF + f] : 0.0f; }

    f32x4 acc[4][8];
#pragma unroll
    for (int mi = 0; mi < 4; ++mi)
#pragma unroll
      for (int nj = 0; nj < 8; ++nj) acc[mi][nj] = (f32x4){0.f, 0.f, 0.f, 0.f};

    const unsigned short* bbase_g = cbt + ((size_t)f * IPAD + jbase) * KDIM;

    // stage one 32-col chunk (A: 2 instr, B: 4 instr) into buffer q.
    // source pre-swizzled: LDS slot s=(p*256+t) <- global (s>>2, (s&3)^((s>>2)&3))
#define STAGE32(q, c0)                                                                \
    {                                                                                 \
      char* Ad = smem + (q) * 24576;                                                  \
      char* Bd = Ad + 8192;                                                           \
      _Pragma("unroll")                                                               \
      for (int p = 0; p < 2; ++p) {                                                   \
        int s = p * 256 + t;                                                          \
        int r = s >> 2, sg = s & 3;                                                   \
        GLOAD_LDS16(abase_g + (size_t)r * KDIM + (c0) + ((sg ^ (r & 3)) << 3),        \
                    Ad + p * 4096 + (w << 10));                                       \
      }                                                                               \
      _Pragma("unroll")                                                               \
      for (int p = 0; p < 4; ++p) {                                                   \
        int s = p * 256 + t;                                                          \
        int r = s >> 2, sg = s & 3;                                                   \
        GLOAD_LDS16(bbase_g + (size_t)r * KDIM + (c0) + ((sg ^ (r & 3)) << 3),        \
                    Bd + p * 4096 + (w << 10));                                       \
      }                                                                               \
    }

    STAGE32(0, 0);                    // prologue: steps 0,1 in flight
    STAGE32(1, 32);

    for (int m = 0; m < 16; ++m) {
      const int cur = m % 3;
      const unsigned short* Al = (const unsigned short*)(smem + cur * 24576);
      const unsigned short* Bl = (const unsigned short*)(smem + cur * 24576 + 8192);
      // #1: all waves done reading the buffer about to be restaged (step m-1's)
      __builtin_amdgcn_s_barrier();
      if (m < 14) {
        STAGE32((m + 2) % 3, (m + 2) * 32);
        // wait the OLDEST 6 (current buffer); 12 younger stay in flight
        asm volatile("s_waitcnt vmcnt(12)" ::: "memory");
      } else if (m == 14) {
        asm volatile("s_waitcnt vmcnt(6)" ::: "memory");
      } else {
        asm volatile("s_waitcnt vmcnt(0)" ::: "memory");
      }
      // #2: every wave has waited its own loads -> buf[cur] fully populated
      __builtin_amdgcn_s_barrier();
      __builtin_amdgcn_sched_barrier(0);   // keep ds_reads below the fence
      bf16x8 a[4];
#pragma unroll
      for (int mi = 0; mi < 4; ++mi)
        a[mi] = *(const bf16x8*)(Al + arow[mi] * 32 + ((lq ^ (arow[mi] & 3)) << 3));
#pragma unroll
      for (int nj = 0; nj < 8; ++nj) {
        bf16x8 b = *(const bf16x8*)(Bl + brow[nj] * 32 + ((lq ^ (brow[nj] & 3)) << 3));
#pragma unroll
        for (int mi = 0; mi < 4; ++mi)
          acc[mi][nj] = __builtin_amdgcn_mfma_f32_16x16x32_bf16(a[mi], b, acc[mi][nj], 0, 0, 0);
      }
    }
#undef STAGE32

    // epilogue + scan: two phases of 128 j, all 256 threads scan
#pragma unroll
    for (int ph = 0; ph < 2; ++ph) {
      __syncthreads();
      if (wj == ph) {                          // these waves hold block-j [ph*128, +128)
#pragma unroll
        for (int mi = 0; mi < 4; ++mi) {
#pragma unroll
          for (int nj = 0; nj < 8; ++nj) {
#pragma unroll
            for (int r = 0; r < 4; ++r) {
              int row = wi * 64 + mi * 16 + lq * 4 + r;   // C: col=lane&15, row=quad*4+reg
              int col = nj * 16 + lrow;
              int q = col >> 2, rr = col & 3;
              Dl[row * 128 + (((q ^ (row & 7))) << 2) + rr] = acc[mi][nj][r];
            }
          }
        }
      }
      __syncthreads();
      if (rowok) {
        const int j0 = jbase + ph * 128 + half * 64;
        int cnt = jlimit - j0; if (cnt > 64) cnt = 64;
        for (int bb = 0; bb < 16; ++bb) {
          const int bo = bb * 4;
          if (bo >= cnt) break;
          const int qq = half * 16 + bb;
          const float4 g4 = *(const float4*)&Dl[ii * 128 + ((qq ^ (ii & 7)) << 2)];
          const float4 s4 = *(const float4*)&sqj[ph * 128 + half * 64 + bo];
          float d0 = fmaxf(fmaf(-2.0f, g4.x, sqi + s4.x), 0.0f);
          float d1 = fmaxf(fmaf(-2.0f, g4.y, sqi + s4.y), 0.0f);
          float d2 = fmaxf(fmaf(-2.0f, g4.z, sqi + s4.z), 0.0f);
          float d3 = fmaxf(fmaf(-2.0f, g4.w, sqi + s4.w), 0.0f);
          const int rem = cnt - bo;
          if (rem < 4) d3 = __builtin_inff();
          if (rem < 3) d2 = __builtin_inff();
          if (rem < 2) d1 = __builtin_inff();
          float mn = fminf(fminf(d0, d1), fminf(d2, d3));
          if (mn <= bv[NCAND - 1]) {           // gate; exact lex insert inside
            float dd[4] = {d0, d1, d2, d3};
#pragma unroll
            for (int e = 0; e < 4; ++e) {      // ascending j within the quad
              float d = dd[e]; int jg = j0 + bo + e;
              if (d < bv[NCAND - 1] || (d == bv[NCAND - 1] && jg < bi[NCAND - 1])) {
                float cv = d; int ci = jg;
#pragma unroll
                for (int k = 0; k < NCAND; ++k) {
                  bool lt = (cv < bv[k]) || (cv == bv[k] && ci < bi[k]);
                  float tv = lt ? bv[k] : cv; int ti = lt ? bi[k] : ci;
                  bv[k] = lt ? cv : bv[k];    bi[k] = lt ? ci : bi[k];
                  cv = tv; ci = ti;
                }
              }
            }
          }
        }
      }
    }
  }

  // merge the two j-half partial top-10s (lex-exact == chunk top-10)
  __syncthreads();
  if (half == 1 && rowok) {
    float* wrow = &Dl[ii * 128];
#pragma unroll
    for (int k = 0; k < NCAND; ++k) { wrow[k] = bv[k]; *(int*)&wrow[NCAND + k] = bi[k]; }
  }
  __syncthreads();
  if (half == 0 && rowok) {
    const float* wrow = &Dl[ii * 128];
    float ov[NCAND]; int oi[NCAND];
#pragma unroll
    for (int k = 0; k < NCAND; ++k) { ov[k] = wrow[k]; oi[k] = *(const int*)&wrow[NCAND + k]; }
    float mv[NCAND]; int mj[NCAND];
    int p = 0, q = 0;
#pragma unroll
    for (int k = 0; k < NCAND; ++k) {          // two-pointer lex merge, pick 10 smallest
      bool mine = (q >= NCAND) || ((p < NCAND) &&
                  ((bv[p] < ov[q]) || (bv[p] == ov[q] && bi[p] < oi[q])));
      mv[k] = mine ? bv[p] : ov[q];
      mj[k] = mine ? bi[p] : oi[q];
      p += mine ? 1 : 0; q += mine ? 0 : 1;
    }
    (void)mv;
    // sort the 10 candidate j's ascending (odd-even transposition)
#pragma unroll
    for (int r = 0; r < NCAND; ++r) {
#pragma unroll
      for (int k = 0; k + 1 < NCAND; ++k) {
        if (((k ^ r) & 1) == 0) {
          int lo = min(mj[k], mj[k + 1]);
          int hi = max(mj[k], mj[k + 1]);
          mj[k] = lo; mj[k + 1] = hi;
        }
      }
    }
    int* dst = cand + ((size_t)(ibase + ii) * CF + f) * NCTOT + jc * NCAND;
#pragma unroll
    for (int k = 0; k < NCAND; ++k) dst[k] = mj[k];
  }
}

// ------------------------------------------- k5: exact distances, wave-cooperative
// v9: 8 lanes per candidate-pair. Lane k covers c in {32n + 4k .. 4k+3},
// n=0..15 -> lanes 0..7 read one fully-used 128B line per instr (vs 64
// scattered lines in v8). Per-lane ascending-c fmaf chain, shfl_xor butterfly
// (1,2,4), lane 0 applies d = fmaf(-2,g,sqi+sqj), clamp, store. Same
// dval/cand layout; distances reassociated (ranking margins >> rounding).
__global__ __launch_bounds__(256) void refine_dist_kernel(const float* __restrict__ ct,
                                                          const float* __restrict__ sq,
                                                          const int* __restrict__ cand,
                                                          float* __restrict__ dval) {
  const int NWG = (F_TOT * CF * (NCTOT / 2)) / 32;   // 10000, %8 == 0
  int orig = blockIdx.x;
  int bid = (orig & 7) * (NWG / 8) + (orig >> 3);    // bijective XCD chunking
  int u = bid * 32 + (threadIdx.x >> 3);             // unit 0..319999
  const int k = threadIdx.x & 7;
  // f-major: u = f*(2000*10) + i*10 + m
  int f = u / (F_TOT * (NCTOT / 2));
  int y = u - f * (F_TOT * (NCTOT / 2));
  int i = y / (NCTOT / 2);
  int m = y - i * (NCTOT / 2);
  int pf = i * CF + f;
  int j0 = cand[(size_t)pf * NCTOT + 2 * m];
  int j1 = cand[(size_t)pf * NCTOT + 2 * m + 1];
  const float* a = ct + ((size_t)f * F_TOT + i) * KDIM + k * 4;
  const float* p = ct + ((size_t)f * F_TOT + j0) * KDIM + k * 4;
  const float* q = ct + ((size_t)f * F_TOT + j1) * KDIM + k * 4;
  float g0 = 0.0f, g1 = 0.0f;
#pragma unroll
  for (int n = 0; n < 16; ++n) {
    float4 av = *(const float4*)(a + n * 32);
    float4 pv = *(const float4*)(p + n * 32);
    float4 qv = *(const float4*)(q + n * 32);
    g0 = fmaf(av.x, pv.x, g0); g1 = fmaf(av.x, qv.x, g1);
    g0 = fmaf(av.y, pv.y, g0); g1 = fmaf(av.y, qv.y, g1);
    g0 = fmaf(av.z, pv.z, g0); g1 = fmaf(av.z, qv.z, g1);
    g0 = fmaf(av.w, pv.w, g0); g1 = fmaf(av.w, qv.w, g1);
  }
#pragma unroll
  for (int off = 1; off < 8; off <<= 1) {
    g0 += __shfl_xor(g0, off);
    g1 += __shfl_xor(g1, off);
  }
  if (k == 0) {
    float sqi = sq[i * CF + f];
    float d0 = fmaf(-2.0f, g0, sqi + sq[j0 * CF + f]); d0 = fmaxf(d0, 0.0f);
    float d1 = fmaf(-2.0f, g1, sqi + sq[j1 * CF + f]); d1 = fmaxf(d1, 0.0f);
    dval[(size_t)pf * NCTOT + 2 * m]     = d0;
    dval[(size_t)pf * NCTOT + 2 * m + 1] = d1;
  }
}

// ------------------------------------------- k6: top-8 select (ascending-j, strict <)
__global__ __launch_bounds__(256) void select_kernel(const float* __restrict__ dval,
                                                     const int* __restrict__ cand,
                                                     int* __restrict__ fidx) {
  int pf = blockIdx.x * 256 + threadIdx.x;   // (i*16+f), 0..31999
  if (pf >= F_TOT * CF) return;
  int i = pf >> 4, f = pf & 15;
  float bval[NB_K]; int bidx[NB_K];
#pragma unroll
  for (int k = 0; k < NB_K; ++k) { bval[k] = __builtin_inff(); bidx[k] = 0; }
#pragma unroll
  for (int m = 0; m < NCTOT; ++m) {          // ascending j (chunks disjoint ascending)
    float d = dval[(size_t)pf * NCTOT + m];
    int j = cand[(size_t)pf * NCTOT + m];
    if (d < bval[NB_K - 1]) {
      float cv = d; int ci = j;
#pragma unroll
      for (int k = 0; k < NB_K; ++k)
        if (cv < bval[k]) {
          float tv = bval[k]; bval[k] = cv; cv = tv;
          int ti = bidx[k]; bidx[k] = ci; ci = ti;
        }
    }
  }
#pragma unroll
  for (int k = 0; k < NB_K; ++k)
    fidx[((size_t)i * NB_K + k) * CF + f] = bidx[k];
}

// ---------------------------------------------------------------- k7: gather
__global__ __launch_bounds__(256) void gather_kernel(const float* __restrict__ inputs,
                                                     const int* __restrict__ fidx,
                                                     float* __restrict__ out) {
  int b = blockIdx.y;
  int x = blockIdx.x * 256 + threadIdx.x;    // m*16+c
  int c = x & 15;
  int n = fidx[x];
  out[(size_t)b * (F_TOT * NB_K * CF) + x] =
      inputs[(size_t)b * (F_TOT * CF) + n * CF + c];
}

// ---------------------------------------------------------------- launcher
extern "C" void kernel_launch(void* const* d_in, const int* in_sizes, int n_in,
                              void* d_out, int out_size, void* d_ws, size_t ws_size,
                              hipStream_t stream) {
  const float* inputs = (const float*)d_in[0];   // (64, 2000, 16)
  const float* coords = (const float*)d_in[1];   // (512, 2000, 16)
  float* out = (float*)d_out;

  unsigned short* cbt = (unsigned short*)d_out;  // 16*2048*512 bf16 (phase 1)
  float* ct = (float*)d_out;                     // 16*2000*512 f32 (phase 2, == out_size)

  float* sq = (float*)d_ws;                      // 32768 floats
  int* cand = (int*)d_ws + 32768;                // 32000*20 ints
  float* dval = (float*)d_ws + 32768 + 32000 * NCTOT; // 32000*20 floats
  int* fidx = (int*)d_ws + 32768 + 2 * 32000 * NCTOT; // 256000 ints

  sq_kernel<<<F_TOT, 256, 0, stream>>>(coords, sq);
  cvt_bf16_kernel<<<dim3(IPAD / 16, KDIM / 32), 256, 0, stream>>>(coords, cbt);
  approx_kernel<<<512, 256, 0, stream>>>(cbt, sq, cand);
  cvt_f32t_kernel<<<dim3(F_TOT / 16, KDIM / 32), 256, 0, stream>>>(coords, ct);
  refine_dist_kernel<<<(F_TOT * CF * (NCTOT / 2)) / 32, 256, 0, stream>>>(ct, sq, cand, dval);
  select_kernel<<<(F_TOT * CF + 255) / 256, 256, 0, stream>>>(dval, cand, fidx);
  dim3 g7((F_TOT * NB_K * CF) / 256, 64);
  gather_kernel<<<g7, 256, 0, stream>>>(inputs, fidx, out);
}